// Round 1
// baseline (356.266 us; speedup 1.0000x reference)
//
#include <hip/hip_runtime.h>
#include <math.h>

// ---------------------------------------------------------------------------
// RecursiveEncoder forward, fp16 MFMA pipeline. Round 4:
//  - k1: child rows stored PERMUTED (m*8+p) so the masked max-pool runs
//    entirely in registers (parent = i+4*(q&1), child = 2*mt+(q>>1), all
//    compile-time reg indices) + one shfl_xor(32) combine. Removes the
//    feat->LDS re-scatter, the scalar maxpool reads, and 2 of 3 barriers.
//  - k2: fully register-resident transposed chain Y^T = W^T x X^T.
//    Wave owns 16 batch cols; weights stream as A (8-deep rolling prefetch);
//    stage-to-stage transpose via 8KB wave-PRIVATE swizzled LDS scratch
//    (no __syncthreads at all). mu/logvar/sampler epilogue in registers,
//    eps/out as quad-lane-coalesced float4.
// ---------------------------------------------------------------------------

#define NPAR  32768
#define LDA1  328        // k1 activation row (halfs): K=320 + 8 pad
#define LDA2  264        // xbuf row (halfs): K=256 + 8 pad
// ws layout (halfs):
#define W1T_OFF   0                  // [256][320]
#define W2T_OFF   81920              // 4 x [256][256]
#define WBX_OFF   (81920 + 4*65536)  // [256][32]  = 344064
#define XBUF_OFF  (WBX_OFF + 8192)   // = 352256; [NPAR][264]

typedef _Float16 f16;
typedef _Float16 f16x8 __attribute__((ext_vector_type(8)));
typedef _Float16 f16x4 __attribute__((ext_vector_type(4)));
typedef float    f32x4 __attribute__((ext_vector_type(4)));

__device__ __forceinline__ f32x4 mfma16(f16x8 a, f16x8 b, f32x4 c) {
    return __builtin_amdgcn_mfma_f32_16x16x32_f16(a, b, c, 0, 0, 0);
}

// ---------------- kconv: dense transposed f16 weights ------------------------
__global__ void kconv(const float* __restrict__ W1, const float* __restrict__ W2,
                      const float* __restrict__ Ws1, const float* __restrict__ Wmu,
                      const float* __restrict__ Wvar, const float* __restrict__ Wbox,
                      f16* __restrict__ ws) {
    int idx = blockIdx.x * 256 + threadIdx.x;
    if (idx < 81920) {                       // W1T[n][k] = W1[k][n], k<320
        int k = idx >> 8, n = idx & 255;
        ws[W1T_OFF + n * 320 + k] = (f16)W1[idx];
    } else if (idx < WBX_OFF) {
        int r = idx - 81920;
        int wsel = r >> 16, r2 = r & 65535;
        int k = r2 >> 8, n = r2 & 255;
        const float* s = (wsel == 0) ? W2 : (wsel == 1) ? Ws1 : (wsel == 2) ? Wmu : Wvar;
        ws[W2T_OFF + wsel * 65536 + n * 256 + k] = (f16)s[r2];
    } else if (idx < XBUF_OFF) {             // WboxT[n][32], zero-padded k>=10
        int r = idx - WBX_OFF;
        int k = r >> 8, n = r & 255;
        float v = (k < 10) ? Wbox[r] : 0.f;
        ws[WBX_OFF + n * 32 + k] = (f16)v;
    }
}

// ---------------- k1: leaf MFMA + K=320 GEMM (one-hot fused) + reg max-pool --
// block = 8 parents = 80 rows; grid 4096; 256 thr (4 waves, each N=64)
// Row PERMUTATION: child (p,m) (p=parent 0..7, m=child 0..9) lives at
// lA row d = m*8 + p. Then C row mt*16+q*4+i has p=i+4*(q&1), m=2*mt+(q>>1).
__global__ __launch_bounds__(256, 2)
void k1(const float* __restrict__ box, const float* __restrict__ bbox,
        const float* __restrict__ b1, const int* __restrict__ sem,
        const int* __restrict__ nch, const f16* __restrict__ wsh,
        f16* __restrict__ xbuf) {
    __shared__ __align__(16) f16 lA[80 * LDA1];   // 52480 B
    __shared__ int lnc[8];

    int tid = threadIdx.x, blk = blockIdx.x;
    int w = tid >> 6, lane = tid & 63, q = lane >> 4, r16 = lane & 15;
    const f16* w1t = wsh + W1T_OFF;
    const f16* wbx = wsh + WBX_OFF;

    if (tid < 8) lnc[tid] = nch[blk * 8 + tid];

    float bbv[4], b1v[4];
    #pragma unroll
    for (int nt = 0; nt < 4; nt++) {
        int col = w * 64 + nt * 16 + r16;
        bbv[nt] = bbox[col];
        b1v[nt] = b1[col];
    }

    // ---- leaf: relu(box @ Wbox + bbox), K=32 zero-padded, frags from global
    f32x4 acc[5][4];
    {
        f16x8 bb[4], ab[5];
        #pragma unroll
        for (int nt = 0; nt < 4; nt++)
            bb[nt] = *(const f16x8*)&wbx[(w * 64 + nt * 16 + r16) * 32 + q * 8];
        #pragma unroll
        for (int mt = 0; mt < 5; mt++) {
            const float* bp = box + (size_t)blk * 800 + (mt * 16 + r16) * 10;
            float v[8] = {0.f, 0.f, 0.f, 0.f, 0.f, 0.f, 0.f, 0.f};
            if (q == 0) {
                float2 t0 = *(const float2*)(bp + 0), t1 = *(const float2*)(bp + 2);
                float2 t2 = *(const float2*)(bp + 4), t3 = *(const float2*)(bp + 6);
                v[0] = t0.x; v[1] = t0.y; v[2] = t1.x; v[3] = t1.y;
                v[4] = t2.x; v[5] = t2.y; v[6] = t3.x; v[7] = t3.y;
            } else if (q == 1) {
                float2 t = *(const float2*)(bp + 8);
                v[0] = t.x; v[1] = t.y;
            }
            f16x8 t;
            #pragma unroll
            for (int j = 0; j < 8; j++) t[j] = (f16)v[j];
            ab[mt] = t;
        }
        #pragma unroll
        for (int mt = 0; mt < 5; mt++)
            #pragma unroll
            for (int nt = 0; nt < 4; nt++)
                acc[mt][nt] = mfma16(ab[mt], bb[nt], (f32x4){0.f, 0.f, 0.f, 0.f});
    }
    // leaf -> lA (C-layout scatter, PERMUTED rows d = m*8+p)
    #pragma unroll
    for (int mt = 0; mt < 5; mt++) {
        #pragma unroll
        for (int i = 0; i < 4; i++) {
            int r = mt * 16 + q * 4 + i;        // original child row 0..79
            int p = (r * 205) >> 11;            // r / 10 (exact for r<80)
            int d = (r - 10 * p) * 8 + p;       // permuted row
            #pragma unroll
            for (int nt = 0; nt < 4; nt++) {
                int col = w * 64 + nt * 16 + r16;
                lA[d * LDA1 + col] = (f16)fmaxf(acc[mt][nt][i] + bbv[nt], 0.f);
            }
        }
    }
    // one-hot region k=256..319: tid IS the permuted row d (p=d&7, m=d>>3)
    if (tid < 80) {
        int p8 = tid & 7, m8 = tid >> 3;
        int sid = sem[blk * 80 + p8 * 10 + m8];
        f16x8 z = {(f16)0.f, (f16)0.f, (f16)0.f, (f16)0.f, (f16)0.f, (f16)0.f, (f16)0.f, (f16)0.f};
        #pragma unroll
        for (int j = 0; j < 8; j++) *(f16x8*)&lA[tid * LDA1 + 256 + j * 8] = z;
        lA[tid * LDA1 + 256 + sid] = (f16)1.f;
    }

    // ---- main GEMM: K=320, B streamed global->regs, 3-deep pipeline
    #pragma unroll
    for (int mt = 0; mt < 5; mt++)
        #pragma unroll
        for (int nt = 0; nt < 4; nt++) acc[mt][nt] = (f32x4){0.f, 0.f, 0.f, 0.f};

    f16x8 bs[3][4];
    auto loadB = [&](int c, int s) {
        #pragma unroll
        for (int nt = 0; nt < 4; nt++)
            bs[s][nt] = *(const f16x8*)&w1t[(w * 64 + nt * 16 + r16) * 320 + c * 32 + q * 8];
    };
    loadB(0, 0); loadB(1, 1); loadB(2, 2);
    __syncthreads();                               // lA (leaf + one-hot) visible
    #pragma unroll
    for (int c = 0; c < 10; c++) {
        f16x8 a[5];
        #pragma unroll
        for (int mt = 0; mt < 5; mt++)
            a[mt] = *(const f16x8*)&lA[(mt * 16 + r16) * LDA1 + c * 32 + q * 8];
        int s = c % 3;
        #pragma unroll
        for (int mt = 0; mt < 5; mt++)
            #pragma unroll
            for (int nt = 0; nt < 4; nt++) acc[mt][nt] = mfma16(a[mt], bs[s][nt], acc[mt][nt]);
        if (c + 3 < 10) loadB(c + 3, s);
    }
    // NO barrier: lA never rewritten; epilogue is all in registers.

    // ---- in-register masked max-pool over children
    int qh = q >> 1, qb = q & 1;
    int ncv[4];
    #pragma unroll
    for (int i = 0; i < 4; i++) ncv[i] = lnc[4 * qb + i];   // parent p = i + 4*qb
    float pm[4][4];
    #pragma unroll
    for (int i = 0; i < 4; i++)
        #pragma unroll
        for (int nt = 0; nt < 4; nt++) pm[i][nt] = 0.f;
    #pragma unroll
    for (int mt = 0; mt < 5; mt++) {
        int m = 2 * mt + qh;                                 // child index
        #pragma unroll
        for (int i = 0; i < 4; i++) {
            bool live = m < ncv[i];
            #pragma unroll
            for (int nt = 0; nt < 4; nt++) {
                float v = fmaxf(acc[mt][nt][i] + b1v[nt], 0.f);
                pm[i][nt] = fmaxf(pm[i][nt], live ? v : 0.f);
            }
        }
    }
    // combine even-m partials (q=0,1) with odd-m partials (q=2,3): lane ^ 32
    #pragma unroll
    for (int i = 0; i < 4; i++)
        #pragma unroll
        for (int nt = 0; nt < 4; nt++)
            pm[i][nt] = fmaxf(pm[i][nt], __shfl_xor(pm[i][nt], 32, 64));
    // q=0 writes parents 0..3, q=1 writes parents 4..7 (q=2,3 hold duplicates)
    if (q < 2) {
        #pragma unroll
        for (int i = 0; i < 4; i++) {
            size_t row = (size_t)blk * 8 + 4 * q + i;
            #pragma unroll
            for (int nt = 0; nt < 4; nt++)
                xbuf[row * LDA2 + w * 64 + nt * 16 + r16] = (f16)pm[i][nt];
        }
    }
}

// ---------------- k2: sampler chain, transposed & register-resident ----------
// Y^T = W^T x X^T. Wave owns 16 batch cols (block=64 rows, grid=512).
// A = weights streamed from global (8-deep rolling prefetch); B in regs;
// stage transpose via wave-PRIVATE 8KB swizzled LDS scratch. Zero barriers.
__global__ __launch_bounds__(256, 2)
void k2(const f16* __restrict__ xbuf, const f16* __restrict__ wsh,
        const float* __restrict__ b2, const float* __restrict__ bs1,
        const float* __restrict__ bmu, const float* __restrict__ bvar,
        const float* __restrict__ eps, float* __restrict__ out) {
    __shared__ __align__(16) f16 tr[4][4096];     // [wave][16 cols][256 k], 32 KiB

    int tid = threadIdx.x, blk = blockIdx.x;
    int w = tid >> 6, lane = tid & 63, q = lane >> 4, r16 = lane & 15;
    const f16* w2t   = wsh + W2T_OFF;
    const f16* ws1t  = w2t + 65536;
    const f16* wmut  = w2t + 2 * 65536;
    const f16* wvart = w2t + 3 * 65536;

    int nb  = blk * 64 + w * 16 + r16;            // owned batch row (= C col)
    int swz = (r16 & 7) << 3;                     // XOR swizzle on k (halfs)
    f16* trw = &tr[w][r16 * 256];

    // ---- B0 = x^T fragments straight from global (4 q-lanes tile 128B/row)
    f16x8 B[8];
    #pragma unroll
    for (int c = 0; c < 8; c++)
        B[c] = *(const f16x8*)&xbuf[(size_t)nb * LDA2 + c * 32 + q * 8];

    f32x4 acc[16];
    f16x8 abuf[8];

    // D[row=h][col=batch]: A-frag = wt[(mt*16+r16)*256 + c*32 + q*8]
    auto runGemm = [&](const f16* wt) {
        #pragma unroll
        for (int mt = 0; mt < 16; mt++) acc[mt] = (f32x4){0.f, 0.f, 0.f, 0.f};
        const f16* wbase = wt + r16 * 256 + q * 8;
        #pragma unroll
        for (int t = 0; t < 8; t++)
            abuf[t] = *(const f16x8*)&wbase[(t & 15) * 4096 + (t >> 4) * 32];
        #pragma unroll
        for (int t = 0; t < 128; t++) {           // t = c*16 + mt
            int c = t >> 4, mt = t & 15;
            acc[mt] = mfma16(abuf[t & 7], B[c], acc[mt]);
            if (t + 8 < 128) {
                int t2 = t + 8;
                abuf[t & 7] = *(const f16x8*)&wbase[(t2 & 15) * 4096 + (t2 >> 4) * 32];
            }
        }
    };

    // bias + relu + f16, wave-private transpose to next-stage B fragments
    auto toB = [&](const float* bias) {
        #pragma unroll
        for (int mt = 0; mt < 16; mt++) {
            f32x4 bv = *(const f32x4*)&bias[mt * 16 + q * 4];
            f16x4 y;
            #pragma unroll
            for (int i = 0; i < 4; i++) y[i] = (f16)fmaxf(acc[mt][i] + bv[i], 0.f);
            int k = mt * 16 + q * 4;              // bits 3..5 swizzled, 4-half unit kept
            *(f16x4*)&trw[k ^ swz] = y;
        }
        #pragma unroll
        for (int c = 0; c < 8; c++) {             // 8-half unit kept under swizzle
            int k = c * 32 + q * 8;
            B[c] = *(const f16x8*)&trw[k ^ swz];
        }
    };

    // stage1: parent = relu(x @ W2 + b2)
    runGemm(w2t);  toB(b2);
    // stage2: enc = relu(parent @ Ws1 + bs1)
    runGemm(ws1t); toB(bs1);
    // stage3: mu (kept in registers; B=enc reused for stage4)
    runGemm(wmut);
    f32x4 mu[16];
    #pragma unroll
    for (int mt = 0; mt < 16; mt++) {
        f32x4 bm = *(const f32x4*)&bmu[mt * 16 + q * 4];
        mu[mt] = acc[mt] + bm;
    }
    // stage4: logvar + fused sampler epilogue
    runGemm(wvart);
    #pragma unroll
    for (int mt = 0; mt < 16; mt++) {
        f32x4 bv = *(const f32x4*)&bvar[mt * 16 + q * 4];
        f32x4 ep = *(const f32x4*)&eps[(size_t)nb * 256 + mt * 16 + q * 4];
        f32x4 o1, o2;
        #pragma unroll
        for (int i = 0; i < 4; i++) {
            float lv = acc[mt][i] + bv[i];
            float m_ = mu[mt][i];
            float e  = expf(lv);
            o1[i] = ep[i] * sqrtf(e) + m_;
            o2[i] = 1.f + lv - m_ * m_ - e;
        }
        *(f32x4*)&out[(size_t)nb * 512 + mt * 16 + q * 4] = o1;
        *(f32x4*)&out[(size_t)nb * 512 + 256 + mt * 16 + q * 4] = o2;
    }
}

// ---------------------------------------------------------------------------
extern "C" void kernel_launch(void* const* d_in, const int* in_sizes, int n_in,
                              void* d_out, int out_size, void* d_ws, size_t ws_size,
                              hipStream_t stream) {
    const float* box  = (const float*)d_in[0];
    const float* eps  = (const float*)d_in[1];
    const float* Wbox = (const float*)d_in[2];
    const float* bbox = (const float*)d_in[3];
    const float* W1   = (const float*)d_in[4];
    const float* b1   = (const float*)d_in[5];
    const float* W2   = (const float*)d_in[6];
    const float* b2   = (const float*)d_in[7];
    const float* Ws1  = (const float*)d_in[8];
    const float* bs1  = (const float*)d_in[9];
    const float* Wmu  = (const float*)d_in[10];
    const float* bmu  = (const float*)d_in[11];
    const float* Wvar = (const float*)d_in[12];
    const float* bvar = (const float*)d_in[13];
    const int*   sem  = (const int*)d_in[14];
    const int*   nch  = (const int*)d_in[15];

    f16* wsh  = (f16*)d_ws;
    f16* xbuf = wsh + XBUF_OFF;

    kconv<<<XBUF_OFF / 256, 256, 0, stream>>>(W1, W2, Ws1, Wmu, Wvar, Wbox, wsh);
    k1<<<NPAR / 8, 256, 0, stream>>>(box, bbox, b1, sem, nch, wsh, xbuf);
    k2<<<NPAR / 64, 256, 0, stream>>>(xbuf, wsh, b2, bs1, bmu, bvar, eps, (float*)d_out);
}

// Round 2
// 218.755 us; speedup vs baseline: 1.6286x; 1.6286x over previous
//
#include <hip/hip_runtime.h>
#include <math.h>

// ---------------------------------------------------------------------------
// RecursiveEncoder forward, fp16 MFMA pipeline. Round 5:
//  - Weights stored in MFMA FRAGMENT ORDER by kconv: the 16B fragment each
//    lane needs is at base + lane*16B, so every weight load is one contiguous
//    1KB wave transaction (was: 64-line scatter at 512B lane stride). This
//    attacks the L2-latency serialization both k1 and k2 counters showed.
//  - k1: round-4 structure kept (permuted rows m*8+p, in-register masked
//    max-pool + shfl_xor(32), single barrier), frag-order weight loads.
//  - k2: reverted to the proven round-3 structure (M=32/block, LDS act
//    ping-pong, 4-stage chain), frag-order weight loads only change.
// ---------------------------------------------------------------------------

#define NPAR  32768
#define LDA1  328        // k1 activation row (halfs): K=320 + 8 pad
#define LDA2  264        // xbuf row (halfs): K=256 + 8 pad
// ws layout (halfs):
#define W1F_OFF   0                  // frag-order W1^T: ((n16*10+c)*64+lane)*8
#define W2F_OFF   81920              // 4 x frag-order [((n16*8+c)*64+lane)*8]
#define WBX_OFF   (81920 + 4*65536)  // frag-order Wbox^T: ((n16*64+lane))*8
#define XBUF_OFF  (WBX_OFF + 8192)   // = 352256; [NPAR][264]

typedef _Float16 f16;
typedef _Float16 f16x8 __attribute__((ext_vector_type(8)));
typedef float    f32x4 __attribute__((ext_vector_type(4)));

__device__ __forceinline__ void async16(const void* g, void* l) {
    __builtin_amdgcn_global_load_lds((const __attribute__((address_space(1))) void*)g,
                                     (__attribute__((address_space(3))) void*)l, 16, 0, 0);
}
__device__ __forceinline__ f32x4 mfma16(f16x8 a, f16x8 b, f32x4 c) {
    return __builtin_amdgcn_mfma_f32_16x16x32_f16(a, b, c, 0, 0, 0);
}

// ---------------- kconv: fragment-ordered f16 weights ------------------------
// Fragment layout: for col-tile n16 (16 cols), k-chunk c (32 k), lane=q*16+r16
// holds halfs j=0..7 of W^T[n16*16+r16][c*32+q*8+j]  (= W[k][n]).
__global__ void kconv(const float* __restrict__ W1, const float* __restrict__ W2,
                      const float* __restrict__ Ws1, const float* __restrict__ Wmu,
                      const float* __restrict__ Wvar, const float* __restrict__ Wbox,
                      f16* __restrict__ ws) {
    int idx = blockIdx.x * 256 + threadIdx.x;
    if (idx < 81920) {                       // W1F (K=320: 10 chunks)
        int j = idx & 7, lane = (idx >> 3) & 63, t = idx >> 9;   // t = n16*10+c
        int c = t % 10, n16 = t / 10;
        int k = c * 32 + (lane >> 4) * 8 + j;
        int n = n16 * 16 + (lane & 15);
        ws[idx] = (f16)W1[k * 256 + n];
    } else if (idx < WBX_OFF) {              // W2/Ws1/Wmu/Wvar (K=256: 8 chunks)
        int r = idx - 81920;
        int wsel = r >> 16, r2 = r & 65535;
        const float* s = (wsel == 0) ? W2 : (wsel == 1) ? Ws1 : (wsel == 2) ? Wmu : Wvar;
        int j = r2 & 7, lane = (r2 >> 3) & 63, c = (r2 >> 9) & 7, n16 = r2 >> 12;
        int k = c * 32 + (lane >> 4) * 8 + j;
        int n = n16 * 16 + (lane & 15);
        ws[idx] = (f16)s[k * 256 + n];
    } else if (idx < XBUF_OFF) {             // WboxF (K=32 zero-padded, 1 chunk)
        int r = idx - WBX_OFF;
        int j = r & 7, lane = (r >> 3) & 63, n16 = r >> 9;
        int k = (lane >> 4) * 8 + j;
        int n = n16 * 16 + (lane & 15);
        ws[idx] = (f16)((k < 10) ? Wbox[k * 256 + n] : 0.f);
    }
}

// ---------------- k1: leaf MFMA + K=320 GEMM (one-hot fused) + reg max-pool --
// block = 8 parents = 80 rows; grid 4096; 256 thr (4 waves, each N=64)
// Row PERMUTATION: child (p,m) lives at lA row d = m*8 + p. Then C row
// mt*16+q*4+i has p = i+4*(q&1), m = 2*mt+(q>>1)  (all compile-time indices).
__global__ __launch_bounds__(256, 2)
void k1(const float* __restrict__ box, const float* __restrict__ bbox,
        const float* __restrict__ b1, const int* __restrict__ sem,
        const int* __restrict__ nch, const f16* __restrict__ wsh,
        f16* __restrict__ xbuf) {
    __shared__ __align__(16) f16 lA[80 * LDA1];   // 52480 B
    __shared__ int lnc[8];

    int tid = threadIdx.x, blk = blockIdx.x;
    int w = tid >> 6, lane = tid & 63, q = lane >> 4, r16 = lane & 15;
    const f16* w1f = wsh + W1F_OFF;
    const f16* wbxf = wsh + WBX_OFF;

    if (tid < 8) lnc[tid] = nch[blk * 8 + tid];

    float bbv[4], b1v[4];
    #pragma unroll
    for (int nt = 0; nt < 4; nt++) {
        int col = w * 64 + nt * 16 + r16;
        bbv[nt] = bbox[col];
        b1v[nt] = b1[col];
    }

    // ---- leaf: relu(box @ Wbox + bbox), K=32 zero-padded, coalesced frags
    f32x4 acc[5][4];
    {
        f16x8 bb[4], ab[5];
        #pragma unroll
        for (int nt = 0; nt < 4; nt++)
            bb[nt] = *(const f16x8*)&wbxf[((w * 4 + nt) * 64 + lane) * 8];
        #pragma unroll
        for (int mt = 0; mt < 5; mt++) {
            const float* bp = box + (size_t)blk * 800 + (mt * 16 + r16) * 10;
            float v[8] = {0.f, 0.f, 0.f, 0.f, 0.f, 0.f, 0.f, 0.f};
            if (q == 0) {
                float2 t0 = *(const float2*)(bp + 0), t1 = *(const float2*)(bp + 2);
                float2 t2 = *(const float2*)(bp + 4), t3 = *(const float2*)(bp + 6);
                v[0] = t0.x; v[1] = t0.y; v[2] = t1.x; v[3] = t1.y;
                v[4] = t2.x; v[5] = t2.y; v[6] = t3.x; v[7] = t3.y;
            } else if (q == 1) {
                float2 t = *(const float2*)(bp + 8);
                v[0] = t.x; v[1] = t.y;
            }
            f16x8 t;
            #pragma unroll
            for (int j = 0; j < 8; j++) t[j] = (f16)v[j];
            ab[mt] = t;
        }
        #pragma unroll
        for (int mt = 0; mt < 5; mt++)
            #pragma unroll
            for (int nt = 0; nt < 4; nt++)
                acc[mt][nt] = mfma16(ab[mt], bb[nt], (f32x4){0.f, 0.f, 0.f, 0.f});
    }
    // leaf -> lA (C-layout scatter, PERMUTED rows d = m*8+p)
    #pragma unroll
    for (int mt = 0; mt < 5; mt++) {
        #pragma unroll
        for (int i = 0; i < 4; i++) {
            int r = mt * 16 + q * 4 + i;        // original child row 0..79
            int p = (r * 205) >> 11;            // r / 10 (exact for r<80)
            int d = (r - 10 * p) * 8 + p;       // permuted row
            #pragma unroll
            for (int nt = 0; nt < 4; nt++) {
                int col = w * 64 + nt * 16 + r16;
                lA[d * LDA1 + col] = (f16)fmaxf(acc[mt][nt][i] + bbv[nt], 0.f);
            }
        }
    }
    // one-hot region k=256..319: tid IS the permuted row d (p=d&7, m=d>>3)
    if (tid < 80) {
        int p8 = tid & 7, m8 = tid >> 3;
        int sid = sem[blk * 80 + p8 * 10 + m8];
        f16x8 z = {(f16)0.f, (f16)0.f, (f16)0.f, (f16)0.f, (f16)0.f, (f16)0.f, (f16)0.f, (f16)0.f};
        #pragma unroll
        for (int j = 0; j < 8; j++) *(f16x8*)&lA[tid * LDA1 + 256 + j * 8] = z;
        lA[tid * LDA1 + 256 + sid] = (f16)1.f;
    }

    // ---- main GEMM: K=320, coalesced frag stream, 3-deep pipeline
    #pragma unroll
    for (int mt = 0; mt < 5; mt++)
        #pragma unroll
        for (int nt = 0; nt < 4; nt++) acc[mt][nt] = (f32x4){0.f, 0.f, 0.f, 0.f};

    f16x8 bs[3][4];
    auto loadB = [&](int c, int s) {
        #pragma unroll
        for (int nt = 0; nt < 4; nt++)
            bs[s][nt] = *(const f16x8*)&w1f[(((w * 4 + nt) * 10 + c) * 64 + lane) * 8];
    };
    loadB(0, 0); loadB(1, 1); loadB(2, 2);
    __syncthreads();                               // lA (leaf + one-hot) visible
    #pragma unroll
    for (int c = 0; c < 10; c++) {
        f16x8 a[5];
        #pragma unroll
        for (int mt = 0; mt < 5; mt++)
            a[mt] = *(const f16x8*)&lA[(mt * 16 + r16) * LDA1 + c * 32 + q * 8];
        int s = c % 3;
        #pragma unroll
        for (int mt = 0; mt < 5; mt++)
            #pragma unroll
            for (int nt = 0; nt < 4; nt++) acc[mt][nt] = mfma16(a[mt], bs[s][nt], acc[mt][nt]);
        if (c + 3 < 10) loadB(c + 3, s);
    }
    // NO barrier: lA never rewritten; epilogue is all in registers.

    // ---- in-register masked max-pool over children
    int qh = q >> 1, qb = q & 1;
    int ncv[4];
    #pragma unroll
    for (int i = 0; i < 4; i++) ncv[i] = lnc[4 * qb + i];   // parent p = i + 4*qb
    float pm[4][4];
    #pragma unroll
    for (int i = 0; i < 4; i++)
        #pragma unroll
        for (int nt = 0; nt < 4; nt++) pm[i][nt] = 0.f;
    #pragma unroll
    for (int mt = 0; mt < 5; mt++) {
        int m = 2 * mt + qh;                                 // child index
        #pragma unroll
        for (int i = 0; i < 4; i++) {
            bool live = m < ncv[i];
            #pragma unroll
            for (int nt = 0; nt < 4; nt++) {
                float v = fmaxf(acc[mt][nt][i] + b1v[nt], 0.f);
                pm[i][nt] = fmaxf(pm[i][nt], live ? v : 0.f);
            }
        }
    }
    // combine even-m partials (q=0,1) with odd-m partials (q=2,3): lane ^ 32
    #pragma unroll
    for (int i = 0; i < 4; i++)
        #pragma unroll
        for (int nt = 0; nt < 4; nt++)
            pm[i][nt] = fmaxf(pm[i][nt], __shfl_xor(pm[i][nt], 32, 64));
    // q=0 writes parents 0..3, q=1 writes parents 4..7 (q=2,3 hold duplicates)
    if (q < 2) {
        #pragma unroll
        for (int i = 0; i < 4; i++) {
            size_t row = (size_t)blk * 8 + 4 * q + i;
            #pragma unroll
            for (int nt = 0; nt < 4; nt++)
                xbuf[row * LDA2 + w * 64 + nt * 16 + r16] = (f16)pm[i][nt];
        }
    }
}

// ---------------- k2: sampler chain, M=32/block, coalesced frag streams ------
// grid 1024; 256 thr; LDS = 2 x 16896 B only
__global__ __launch_bounds__(256, 2)
void k2(const f16* __restrict__ xbuf, const f16* __restrict__ wsh,
        const float* __restrict__ b2, const float* __restrict__ bs1,
        const float* __restrict__ bmu, const float* __restrict__ bvar,
        const float* __restrict__ eps, float* __restrict__ out) {
    __shared__ __align__(16) f16 actA[32 * LDA2];
    __shared__ __align__(16) f16 actB[32 * LDA2];

    int tid = threadIdx.x, blk = blockIdx.x;
    int w = tid >> 6, lane = tid & 63, q = lane >> 4, r16 = lane & 15;
    const f16* w2f   = wsh + W2F_OFF;
    const f16* ws1f  = w2f + 65536;
    const f16* wmuf  = w2f + 2 * 65536;
    const f16* wvarf = w2f + 3 * 65536;

    float b2v[4], bs1v[4], bmv[4], bvv[4];
    #pragma unroll
    for (int nt = 0; nt < 4; nt++) {
        int col = w * 64 + nt * 16 + r16;
        b2v[nt] = b2[col]; bs1v[nt] = bs1[col];
        bmv[nt] = bmu[col]; bvv[nt] = bvar[col];
    }

    {   // stage x tile (16896 B flat) -> actA
        const char* src = (const char*)(xbuf + (size_t)blk * 32 * LDA2);
        #pragma unroll
        for (int j = 0; j < 5; j++) {
            int idx = tid + j * 256;
            if (idx < 1056) async16(src + idx * 16, (char*)actA + idx * 16);
        }
    }

    f32x4 acc[2][4];
    f16x8 bs[3][4];
    auto loadB = [&](const f16* wt, int c, int s) {
        #pragma unroll
        for (int nt = 0; nt < 4; nt++)
            bs[s][nt] = *(const f16x8*)&wt[(((w * 4 + nt) * 8 + c) * 64 + lane) * 8];
    };
    auto gemm = [&](const f16* A, const f16* wt) {   // caller preloads bs[0..2]
        #pragma unroll
        for (int mt = 0; mt < 2; mt++)
            #pragma unroll
            for (int nt = 0; nt < 4; nt++) acc[mt][nt] = (f32x4){0.f, 0.f, 0.f, 0.f};
        #pragma unroll
        for (int c = 0; c < 8; c++) {
            f16x8 a[2];
            #pragma unroll
            for (int mt = 0; mt < 2; mt++)
                a[mt] = *(const f16x8*)&A[(mt * 16 + r16) * LDA2 + c * 32 + q * 8];
            int s = c % 3;
            #pragma unroll
            for (int mt = 0; mt < 2; mt++)
                #pragma unroll
                for (int nt = 0; nt < 4; nt++) acc[mt][nt] = mfma16(a[mt], bs[s][nt], acc[mt][nt]);
            if (c + 3 < 8) loadB(wt, c + 3, s);
        }
    };

    // stage1: parent = relu(x @ W2 + b2) -> actB
    loadB(w2f, 0, 0); loadB(w2f, 1, 1); loadB(w2f, 2, 2);
    __syncthreads();                               // drains actA staging
    gemm(actA, w2f);
    #pragma unroll
    for (int nt = 0; nt < 4; nt++) {
        int col = w * 64 + nt * 16 + r16;
        #pragma unroll
        for (int mt = 0; mt < 2; mt++)
            #pragma unroll
            for (int i = 0; i < 4; i++)
                actB[(mt * 16 + q * 4 + i) * LDA2 + col] = (f16)fmaxf(acc[mt][nt][i] + b2v[nt], 0.f);
    }
    loadB(ws1f, 0, 0); loadB(ws1f, 1, 1); loadB(ws1f, 2, 2);
    __syncthreads();

    // stage2: enc = relu(parent @ Ws1 + bs1) -> actA
    gemm(actB, ws1f);
    #pragma unroll
    for (int nt = 0; nt < 4; nt++) {
        int col = w * 64 + nt * 16 + r16;
        #pragma unroll
        for (int mt = 0; mt < 2; mt++)
            #pragma unroll
            for (int i = 0; i < 4; i++)
                actA[(mt * 16 + q * 4 + i) * LDA2 + col] = (f16)fmaxf(acc[mt][nt][i] + bs1v[nt], 0.f);
    }
    loadB(wmuf, 0, 0); loadB(wmuf, 1, 1); loadB(wmuf, 2, 2);
    __syncthreads();

    // stage3: mu -> regs
    gemm(actA, wmuf);
    f32x4 mu[2][4];
    #pragma unroll
    for (int mt = 0; mt < 2; mt++)
        #pragma unroll
        for (int nt = 0; nt < 4; nt++) mu[mt][nt] = acc[mt][nt];

    // prefetch eps while stage4 runs
    float ev[2][4][4];
    #pragma unroll
    for (int mt = 0; mt < 2; mt++)
        #pragma unroll
        for (int i = 0; i < 4; i++) {
            size_t grow = (size_t)blk * 32 + mt * 16 + q * 4 + i;
            #pragma unroll
            for (int nt = 0; nt < 4; nt++)
                ev[mt][nt][i] = eps[grow * 256 + w * 64 + nt * 16 + r16];
        }

    // stage4: logvar + fused sampler epilogue (actA unchanged: no barrier)
    loadB(wvarf, 0, 0); loadB(wvarf, 1, 1); loadB(wvarf, 2, 2);
    gemm(actA, wvarf);
    #pragma unroll
    for (int mt = 0; mt < 2; mt++)
        #pragma unroll
        for (int nt = 0; nt < 4; nt++) {
            int col = w * 64 + nt * 16 + r16;
            #pragma unroll
            for (int i = 0; i < 4; i++) {
                size_t grow = (size_t)blk * 32 + mt * 16 + q * 4 + i;
                float m_ = mu[mt][nt][i] + bmv[nt];
                float lv = acc[mt][nt][i] + bvv[nt];
                float e  = expf(lv);
                out[grow * 512 + col]       = ev[mt][nt][i] * sqrtf(e) + m_;
                out[grow * 512 + 256 + col] = 1.f + lv - m_ * m_ - e;
            }
        }
}

// ---------------------------------------------------------------------------
extern "C" void kernel_launch(void* const* d_in, const int* in_sizes, int n_in,
                              void* d_out, int out_size, void* d_ws, size_t ws_size,
                              hipStream_t stream) {
    const float* box  = (const float*)d_in[0];
    const float* eps  = (const float*)d_in[1];
    const float* Wbox = (const float*)d_in[2];
    const float* bbox = (const float*)d_in[3];
    const float* W1   = (const float*)d_in[4];
    const float* b1   = (const float*)d_in[5];
    const float* W2   = (const float*)d_in[6];
    const float* b2   = (const float*)d_in[7];
    const float* Ws1  = (const float*)d_in[8];
    const float* bs1  = (const float*)d_in[9];
    const float* Wmu  = (const float*)d_in[10];
    const float* bmu  = (const float*)d_in[11];
    const float* Wvar = (const float*)d_in[12];
    const float* bvar = (const float*)d_in[13];
    const int*   sem  = (const int*)d_in[14];
    const int*   nch  = (const int*)d_in[15];

    f16* wsh  = (f16*)d_ws;
    f16* xbuf = wsh + XBUF_OFF;

    kconv<<<XBUF_OFF / 256, 256, 0, stream>>>(W1, W2, Ws1, Wmu, Wvar, Wbox, wsh);
    k1<<<NPAR / 8, 256, 0, stream>>>(box, bbox, b1, sem, nch, wsh, xbuf);
    k2<<<NPAR / 32, 256, 0, stream>>>(xbuf, wsh, b2, bs1, bmu, bvar, eps, (float*)d_out);
}